// Round 1
// 24205.307 us; speedup vs baseline: 2.7915x; 2.7915x over previous
//
#include <hip/hip_runtime.h>
#include <hip/hip_bf16.h>
#include <math.h>

// V=32000, E=512, H=1024, T=4096
// Decomposition:
//   1) gather+cast emb rows -> bf16, cast Wih -> bf16
//   2) Gin = X @ Wih^T + (bih+bhh)   (bf16 MFMA GEMM, bf16 out)  [enc, dec]
//   3) persistent flag-synced LSTM recurrence (128 WGs, Whh in VGPRs, fp32)
//      sync via per-access agent-scope coherence (sc1), NOT __threadfence:
//      threadfence at agent scope on gfx950 = full L2 writeback/invalidate
//      per step per WG -> was ~8 us/step. Now: relaxed sc1 stores + vmcnt(0)
//      ack + relaxed flag store (release), relaxed poll + sc1 loads (acquire).
//   4) cast out_W -> bf16 (overlaid on dead Gin buffers), hdec -> bf16
//   5) logits = hs @ out_W^T + out_b (bf16 MFMA GEMM, fp32 out -> d_out)

typedef __attribute__((ext_vector_type(8))) short bf16x8;
typedef __attribute__((ext_vector_type(4))) float f32x4;

#define NWG 128

// ---------------------------------------------------------------- init
__global__ void init_misc(const float* __restrict__ bihE, const float* __restrict__ bhhE,
                          const float* __restrict__ bihD, const float* __restrict__ bhhD,
                          float* __restrict__ biasE, float* __restrict__ biasD,
                          float* __restrict__ henc0, int* __restrict__ flags) {
    int i = blockIdx.x * 256 + threadIdx.x;   // grid 16x256 -> 4096
    if (i < 4096) { biasE[i] = bihE[i] + bhhE[i]; biasD[i] = bihD[i] + bhhD[i]; }
    if (i < 1024) henc0[i] = 0.0f;
    if (i < NWG)  flags[i] = 0;
}

// ------------------------------------------------- gather + cast to bf16
__global__ void gather_cast(const float* __restrict__ emb, const int* __restrict__ seq,
                            __hip_bfloat16* __restrict__ X) {
    int t = blockIdx.x;                 // one row per block, 128 threads
    int row = seq[t];
    const float4* src = (const float4*)(emb + (size_t)row * 512);
    float4 v = src[threadIdx.x];
    __hip_bfloat16 tmp[4];
    tmp[0] = __float2bfloat16(v.x); tmp[1] = __float2bfloat16(v.y);
    tmp[2] = __float2bfloat16(v.z); tmp[3] = __float2bfloat16(v.w);
    __hip_bfloat16* dst = X + (size_t)t * 512 + threadIdx.x * 4;
    *(uint2*)dst = *(uint2*)tmp;
}

// ------------------------------------------------------- float -> bf16
__global__ void f2b(const float* __restrict__ src, __hip_bfloat16* __restrict__ dst, int n4) {
    int i = blockIdx.x * 256 + threadIdx.x;
    if (i < n4) {
        float4 v = ((const float4*)src)[i];
        __hip_bfloat16 tmp[4];
        tmp[0] = __float2bfloat16(v.x); tmp[1] = __float2bfloat16(v.y);
        tmp[2] = __float2bfloat16(v.z); tmp[3] = __float2bfloat16(v.w);
        *(uint2*)(dst + (size_t)i * 4) = *(uint2*)tmp;
    }
}

// ------------------------------------------------------ bf16 MFMA GEMM
// C[M][N] = sum_k A[m][k]*B[n][k] + bias[n];  A:[M,K] bf16, B:[N,K] bf16.
// Block = 256 thr (4 waves), tile 128(M) x 64(N); per wave 32x64 = 2x4 MFMA tiles.
// OUTF: 0 -> bf16 C, 1 -> fp32 C.
template <int OUTF>
__global__ __launch_bounds__(256) void gemm_bt(
    const __hip_bfloat16* __restrict__ Ap, const __hip_bfloat16* __restrict__ Bp_,
    const float* __restrict__ bias, void* __restrict__ C,
    int M, int N, int K) {
    const int lane = threadIdx.x & 63;
    const int wave = threadIdx.x >> 6;
    const int n0 = blockIdx.x * 64;
    const int m0 = blockIdx.y * 128 + wave * 32;
    const int q  = lane >> 4;       // quad 0..3 (k-offset q*8)
    const int lm = lane & 15;

    int rowA0 = m0 + lm;       if (rowA0 >= M) rowA0 = M - 1;
    int rowA1 = m0 + 16 + lm;  if (rowA1 >= M) rowA1 = M - 1;
    const short* A  = (const short*)Ap;
    const short* B  = (const short*)Bp_;
    const short* a0p = A + (size_t)rowA0 * K + q * 8;
    const short* a1p = A + (size_t)rowA1 * K + q * 8;
    const short* bp[4];
#pragma unroll
    for (int tj = 0; tj < 4; ++tj)
        bp[tj] = B + (size_t)(n0 + tj * 16 + lm) * K + q * 8;

    f32x4 acc[2][4] = {};
    for (int kb = 0; kb < K; kb += 32) {
        bf16x8 a0 = *(const bf16x8*)(a0p + kb);
        bf16x8 a1 = *(const bf16x8*)(a1p + kb);
#pragma unroll
        for (int tj = 0; tj < 4; ++tj) {
            bf16x8 b = *(const bf16x8*)(bp[tj] + kb);
            acc[0][tj] = __builtin_amdgcn_mfma_f32_16x16x32_bf16(a0, b, acc[0][tj], 0, 0, 0);
            acc[1][tj] = __builtin_amdgcn_mfma_f32_16x16x32_bf16(a1, b, acc[1][tj], 0, 0, 0);
        }
    }
    // D layout: row_in_tile = q*4 + r, col_in_tile = lm   [measured m89/m91]
#pragma unroll
    for (int tj = 0; tj < 4; ++tj) {
        int col = n0 + tj * 16 + lm;
        float bv = bias ? bias[col] : 0.0f;
#pragma unroll
        for (int ti = 0; ti < 2; ++ti) {
            int rbase = m0 + ti * 16 + q * 4;
#pragma unroll
            for (int r = 0; r < 4; ++r) {
                int row = rbase + r;
                if (row < M) {
                    float v = acc[ti][tj][r] + bv;
                    if (OUTF == 0)
                        ((__hip_bfloat16*)C)[(size_t)row * N + col] = __float2bfloat16(v);
                    else
                        ((float*)C)[(size_t)row * N + col] = v;
                }
            }
        }
    }
}

// ------------------------------------------------ persistent LSTM recurrence
// 128 WGs x 256 thr. WG w owns hidden units [w*8, w*8+8): 32 gate rows of Whh.
// Thread map: chunk = tid&31 -> cols [chunk*32, +32); rgrp = tid>>5 -> rows rgrp*4..+3.
// Weights in VGPRs: wr[4][32]. Sync: flags[w] = completed-step counter (agent scope).
// Coherence protocol (NO __threadfence -> no per-step L2 wbl2/inv storm):
//   writer: h stores as relaxed agent atomics (sc1, write-through to L3)
//           -> s_waitcnt vmcnt(0) (acked at coherence point)
//           -> relaxed agent flag store.
//   reader: relaxed agent flag poll -> sc1 dwordx4 h load (bypasses stale L2).
//   Sound because h stores are acked at L3 before the flag store issues, and
//   h loads issue only after the flag is observed; h rows are write-once.
__global__ __launch_bounds__(256, 1) void lstm_persist(
    const __hip_bfloat16* __restrict__ GinE, const __hip_bfloat16* __restrict__ GinD,
    const float* __restrict__ WhhE, const float* __restrict__ WhhD,
    float* henc, float* hdec, int* flags) {
    __shared__ float lh[33 * 32];   // stride-33: conflict-free lane reads
    __shared__ float pre[32];
    const int tid = threadIdx.x;
    const int w = blockIdx.x;
    const int j0 = w * 8;
    const int chunk = tid & 31;
    const int rgrp = tid >> 5;
    const int c0 = chunk * 32;

    float cst = 0.0f;   // cell state (valid on tid<8)
    float wr[4][32];

    auto load_w = [&](const float* __restrict__ Whh) {
#pragma unroll
        for (int rr = 0; rr < 4; ++rr) {
            int r = rgrp * 4 + rr;            // 0..31
            int qg = r >> 3, jl = r & 7;      // gate, local hidden
            const float4* p = (const float4*)(Whh + (size_t)(qg * 1024 + j0 + jl) * 1024 + c0);
#pragma unroll
            for (int g = 0; g < 8; ++g) {
                float4 v = p[g];
                wr[rr][g * 4 + 0] = v.x; wr[rr][g * 4 + 1] = v.y;
                wr[rr][g * 4 + 2] = v.z; wr[rr][g * 4 + 3] = v.w;
            }
        }
    };

    auto phase = [&](const float* hinb, float* houtb, const __hip_bfloat16* __restrict__ Gin,
                     int nsteps, int flagbase, float* copy0) {
        for (int t = 0; t < nsteps; ++t) {
            const int target = flagbase + t;
            // prefetch Gin[t] for this WG's rows (hidden latency behind poll)
            float gf0 = 0, gf1 = 0, gf2 = 0, gf3 = 0;
            if (tid < 8) {
                const __hip_bfloat16* gp = Gin + (size_t)t * 4096 + j0 + tid;
                gf0 = (float)gp[0]; gf1 = (float)gp[1024];
                gf2 = (float)gp[2048]; gf3 = (float)gp[3072];
            }
            // wave 0 polls all flags (relaxed agent; no acquire fence needed)
            if (tid < 64) {
                while (true) {
                    int a = __hip_atomic_load(flags + tid, __ATOMIC_RELAXED, __HIP_MEMORY_SCOPE_AGENT);
                    int b = __hip_atomic_load(flags + 64 + tid, __ATOMIC_RELAXED, __HIP_MEMORY_SCOPE_AGENT);
                    if (__all(a >= target && b >= target)) break;
                }
            }
            __syncthreads();
            // load h[t] device-coherently (sc1 bypasses any stale local L2);
            // load + waitcnt in ONE asm block so consumers can't slip between.
            const float* hin = hinb + (size_t)t * 1024;
            const float* hp = hin + tid * 4;
            f32x4 hv4;
            asm volatile("global_load_dwordx4 %0, %1, off sc1\n\t"
                         "s_waitcnt vmcnt(0)"
                         : "=&v"(hv4) : "v"(hp) : "memory");
            // stage h[t] into LDS (4 KB, coalesced), stride-33 layout
            {
                int cc = tid >> 3, kk = (tid * 4) & 31;
                float* dst = &lh[cc * 33 + kk];
                dst[0] = hv4[0]; dst[1] = hv4[1]; dst[2] = hv4[2]; dst[3] = hv4[3];
            }
            __syncthreads();
            float hv[32];
#pragma unroll
            for (int k = 0; k < 32; ++k) hv[k] = lh[chunk * 33 + k];  // conflict-free
            float p0 = 0, p1 = 0, p2 = 0, p3 = 0;
#pragma unroll
            for (int k = 0; k < 32; ++k) {
                float h = hv[k];
                p0 = fmaf(wr[0][k], h, p0);
                p1 = fmaf(wr[1][k], h, p1);
                p2 = fmaf(wr[2][k], h, p2);
                p3 = fmaf(wr[3][k], h, p3);
            }
            // reduce across the 32 chunk-lanes (tree stays within each half-wave)
#pragma unroll
            for (int off = 16; off >= 1; off >>= 1) {
                p0 += __shfl_down(p0, off, 64);
                p1 += __shfl_down(p1, off, 64);
                p2 += __shfl_down(p2, off, 64);
                p3 += __shfl_down(p3, off, 64);
            }
            if (chunk == 0) {
                pre[rgrp * 4 + 0] = p0; pre[rgrp * 4 + 1] = p1;
                pre[rgrp * 4 + 2] = p2; pre[rgrp * 4 + 3] = p3;
            }
            __syncthreads();
            if (tid < 8) {
                float xi = pre[tid]      + gf0;
                float xf = pre[8 + tid]  + gf1;
                float xg = pre[16 + tid] + gf2;
                float xo = pre[24 + tid] + gf3;
                float I = 1.0f / (1.0f + __expf(-xi));
                float F = 1.0f / (1.0f + __expf(-xf));
                float G = tanhf(xg);
                float O = 1.0f / (1.0f + __expf(-xo));
                cst = F * cst + I * G;
                float h = O * tanhf(cst);
                // write-through (agent scope) so data reaches the L3 coherence
                // point; then wait for the ack before the flag is raised.
                __hip_atomic_store(&houtb[(size_t)(t + 1) * 1024 + j0 + tid], h,
                                   __ATOMIC_RELAXED, __HIP_MEMORY_SCOPE_AGENT);
                if (copy0 && t == nsteps - 1)
                    __hip_atomic_store(&copy0[j0 + tid], h,
                                       __ATOMIC_RELAXED, __HIP_MEMORY_SCOPE_AGENT);
                asm volatile("s_waitcnt vmcnt(0)" ::: "memory");
            }
            __syncthreads();
            if (tid == 0)
                __hip_atomic_store(flags + w, target + 1, __ATOMIC_RELAXED, __HIP_MEMORY_SCOPE_AGENT);
        }
    };

    load_w(WhhE);
    phase(henc, henc, GinE, 4096, 0, hdec);       // final enc h also -> hdec[0]
    load_w(WhhD);
    phase(hdec, hdec, GinD, 4095, 4096, nullptr);
}

// ---------------------------------------------------------------- launch
extern "C" void kernel_launch(void* const* d_in, const int* in_sizes, int n_in,
                              void* d_out, int out_size, void* d_ws, size_t ws_size,
                              hipStream_t stream) {
    const int*   seq    = (const int*)  d_in[0];
    const float* encEmb = (const float*)d_in[1];
    const float* encWih = (const float*)d_in[2];
    const float* encWhh = (const float*)d_in[3];
    const float* encBih = (const float*)d_in[4];
    const float* encBhh = (const float*)d_in[5];
    const float* decEmb = (const float*)d_in[6];
    const float* decWih = (const float*)d_in[7];
    const float* decWhh = (const float*)d_in[8];
    const float* decBih = (const float*)d_in[9];
    const float* decBhh = (const float*)d_in[10];
    const float* outW   = (const float*)d_in[11];
    const float* outB   = (const float*)d_in[12];
    float* out = (float*)d_out;

    char* ws = (char*)d_ws;
    size_t off = 0;
    auto alloc = [&](size_t bytes) -> void* {
        void* p = ws + off; off += (bytes + 255) & ~(size_t)255; return p;
    };
    float* biasE = (float*)alloc(4096 * 4);
    float* biasD = (float*)alloc(4096 * 4);
    int*   flags = (int*)  alloc(NWG * 4);
    __hip_bfloat16* Xenc  = (__hip_bfloat16*)alloc((size_t)4096 * 512 * 2);
    __hip_bfloat16* Xdec  = (__hip_bfloat16*)alloc((size_t)4096 * 512 * 2);
    __hip_bfloat16* WihEb = (__hip_bfloat16*)alloc((size_t)4096 * 512 * 2);
    __hip_bfloat16* WihDb = (__hip_bfloat16*)alloc((size_t)4096 * 512 * 2);
    float* henc  = (float*)alloc((size_t)4097 * 1024 * 4);
    float* hdec  = (float*)alloc((size_t)4096 * 1024 * 4);
    __hip_bfloat16* Aproj = (__hip_bfloat16*)alloc((size_t)4096 * 1024 * 2);
    __hip_bfloat16* GinE  = (__hip_bfloat16*)alloc((size_t)4096 * 4096 * 2);
    __hip_bfloat16* GinD  = (__hip_bfloat16*)alloc((size_t)4096 * 4096 * 2);
    // out_W bf16 (64 MB) overlays GinE+GinD (contiguous 64 MB, dead after recurrence)
    __hip_bfloat16* outWb = GinE;

    init_misc<<<16, 256, 0, stream>>>(encBih, encBhh, decBih, decBhh, biasE, biasD, henc, flags);
    gather_cast<<<4096, 128, 0, stream>>>(encEmb, seq, Xenc);
    gather_cast<<<4095, 128, 0, stream>>>(decEmb, seq, Xdec);
    f2b<<<2048, 256, 0, stream>>>(encWih, WihEb, 4096 * 512 / 4);
    f2b<<<2048, 256, 0, stream>>>(decWih, WihDb, 4096 * 512 / 4);

    dim3 g1(64, 32);
    gemm_bt<0><<<g1, 256, 0, stream>>>(Xenc, WihEb, biasE, GinE, 4096, 4096, 512);
    gemm_bt<0><<<g1, 256, 0, stream>>>(Xdec, WihDb, biasD, GinD, 4096, 4096, 512);

    lstm_persist<<<NWG, 256, 0, stream>>>(GinE, GinD, encWhh, decWhh, henc, hdec, flags);

    f2b<<<32000, 256, 0, stream>>>(outW, outWb, 32000 * 1024 / 4);
    f2b<<<4095, 256, 0, stream>>>(hdec + 1024, Aproj, 4095 * 1024 / 4);

    dim3 g2(500, 32);
    gemm_bt<1><<<g2, 256, 0, stream>>>(Aproj, outWb, outB, out, 4095, 32000, 1024);
}